// Round 22
// baseline (366.788 us; speedup 1.0000x reference)
//
#include <hip/hip_runtime.h>
#include <hip/hip_bf16.h>

#define Bn 128
#define Tn 512
#define En 100
#define G4 256   // 4*HD
#define Hn 128
#define Kn 12

typedef short bf16x8 __attribute__((ext_vector_type(8)));
typedef float f32x4 __attribute__((ext_vector_type(4)));
// exact type the AMDGCN packed-half builtins use
using h2_t = decltype(__builtin_amdgcn_cvt_pkrtz(0.0f, 0.0f));
union U32H2 { unsigned int u; float f; h2_t h; };

// Raw barrier: lgkmcnt(0) + s_barrier, no vmcnt drain (prefetch survives).
__device__ __forceinline__ void wg_barrier() {
  asm volatile("s_waitcnt lgkmcnt(0)" ::: "memory");
  __builtin_amdgcn_s_barrier();
  asm volatile("" ::: "memory");
}

__device__ __forceinline__ float exp2_hw(float x) {
  float r; asm("v_exp_f32 %0, %1" : "=v"(r) : "v"(x)); return r;
}
__device__ __forceinline__ float rcp_hw(float x) {
  float r; asm("v_rcp_f32 %0, %1" : "=v"(r) : "v"(x)); return r;
}
__device__ __forceinline__ float fast_tanh(float x) {
  return 1.0f - 2.0f * rcp_hw(1.0f + exp2_hw(x * 2.8853900817779268f));
}
__device__ __forceinline__ float fdot2(h2_t a, h2_t b, float c) {
#if __has_builtin(__builtin_amdgcn_fdot2)
  return __builtin_amdgcn_fdot2(a, b, c, false);
#else
  float r;
  asm("v_dot2_f32_f16 %0, %1, %2, %3" : "=v"(r) : "v"(a), "v"(b), "v"(c));
  return r;
#endif
}
// pack 2 floats -> 2 bf16 (RNE) in one u32
__device__ __forceinline__ unsigned int pk2bf(float a, float b) {
  unsigned int ua = __float_as_uint(a); ua += 0x7FFFu + ((ua >> 16) & 1u);
  unsigned int ub = __float_as_uint(b); ub += 0x7FFFu + ((ub >> 16) & 1u);
  return (ua >> 16) | (ub & 0xFFFF0000u);
}

// ---------------- K1: proj via MFMA bf16, 4 token-tiles/block (r21) -------
__global__ __launch_bounds__(256) void proj_kernel(
    const int* __restrict__ sent, const float* __restrict__ embed,
    const float* __restrict__ WihF, const float* __restrict__ WihB,
    const float* __restrict__ bihF, const float* __restrict__ bhhF,
    const float* __restrict__ bihB, const float* __restrict__ bhhB,
    float* __restrict__ xgF, float* __restrict__ xgB, int dirSel) {
  __shared__ __align__(16) unsigned short embS[64][128];
  __shared__ __align__(16) unsigned short wS[128][128];
  __shared__ float bias_s[128];
  const int tid = threadIdx.x;
  const int nhalf = blockIdx.y;
  const int dir = (dirSel >= 0) ? dirSel : (int)blockIdx.z;
  const float* Wih = dir ? WihB : WihF;
  const float* bih = dir ? bihB : bihF;
  const float* bhh = dir ? bhhB : bhhF;
  float* xg = dir ? xgB : xgF;
  const int g0 = nhalf * 128;
  // --- stage W once ---
  {
    const int r = tid >> 1, q = tid & 1;
    const float* wr = Wih + (size_t)(g0 + r) * En;
    for (int c = q; c < 16; c += 2) {
      uint4 wv;
      if (c < 12) {
        const float4 f0 = *(const float4*)(wr + 8 * c);
        const float4 f1 = *(const float4*)(wr + 8 * c + 4);
        wv = make_uint4(pk2bf(f0.x, f0.y), pk2bf(f0.z, f0.w),
                        pk2bf(f1.x, f1.y), pk2bf(f1.z, f1.w));
      } else if (c == 12) {
        float f[8];
#pragma unroll
        for (int j = 0; j < 8; ++j) { const int e = 96 + j; f[j] = (e < En) ? wr[e] : 0.f; }
        wv = make_uint4(pk2bf(f[0], f[1]), pk2bf(f[2], f[3]),
                        pk2bf(f[4], f[5]), pk2bf(f[6], f[7]));
      } else {
        wv = make_uint4(0, 0, 0, 0);
      }
      *(uint4*)&wS[r][8 * (c ^ (r & 7))] = wv;
    }
    if (tid < 128) bias_s[tid] = bih[g0 + tid] + bhh[g0 + tid];
  }
  const int m = tid >> 6;
  const int lane = tid & 63;
  const int lr = lane & 15;
  const int lq = lane >> 4;
  const int t = 16 * m + lr;
  for (int tt = 0; tt < 4; ++tt) {
    const int n0 = (blockIdx.x * 4 + tt) * 64;
    {
      const int tr = tid >> 2, q = tid & 3;
      const int row = sent[n0 + tr];
      const float* er = embed + (size_t)row * En;
      for (int c = q; c < 16; c += 4) {
        uint4 wv;
        if (c < 12) {
          const float4 f0 = *(const float4*)(er + 8 * c);
          const float4 f1 = *(const float4*)(er + 8 * c + 4);
          wv = make_uint4(pk2bf(f0.x, f0.y), pk2bf(f0.z, f0.w),
                          pk2bf(f1.x, f1.y), pk2bf(f1.z, f1.w));
        } else if (c == 12) {
          float f[8];
#pragma unroll
          for (int j = 0; j < 8; ++j) { const int e = 96 + j; f[j] = (e < En) ? er[e] : 0.f; }
          wv = make_uint4(pk2bf(f[0], f[1]), pk2bf(f[2], f[3]),
                          pk2bf(f[4], f[5]), pk2bf(f[6], f[7]));
        } else {
          wv = make_uint4(0, 0, 0, 0);
        }
        *(uint4*)&embS[tr][8 * (c ^ (tr & 7))] = wv;
      }
    }
    __syncthreads();
    f32x4 acc[8] = {};
#pragma unroll
    for (int ks = 0; ks < 4; ++ks) {
      const int cs = 4 * ks + lq;
      const bf16x8 af = *(const bf16x8*)&embS[t][8 * (cs ^ (lr & 7))];
#pragma unroll
      for (int nt = 0; nt < 8; ++nt) {
        const int g = 16 * nt + lr;
        const bf16x8 bf = *(const bf16x8*)&wS[g][8 * (cs ^ (lr & 7))];
        acc[nt] = __builtin_amdgcn_mfma_f32_16x16x32_bf16(af, bf, acc[nt], 0, 0, 0);
      }
    }
    float* xbase = xg + (size_t)(n0 + 16 * m) * G4 + g0;
#pragma unroll
    for (int nt = 0; nt < 8; ++nt) {
      const int g = 16 * nt + lr;
      const float bv = bias_s[g];
#pragma unroll
      for (int j = 0; j < 4; ++j) {
        const int tok = 4 * lq + j;
        xbase[(size_t)tok * G4 + g] = acc[nt][j] + bv;
      }
    }
    __syncthreads();
  }
}

// ---------------- K2: LSTM (f16-dot2, 3 balanced T-chunks) ----------------
// r19 structure; 3 chunks per (dir,b) at 6 waves/SIMD (3 blocks/CU):
// ck0 emits [0,216); ck1 burns [152,216) emits [216,364); ck2 burns
// [300,364) emits [364,512). Wall-path 288->216 steps; issue demand
// 6x213x290 ~ 371k cyc/SIMD ~ within capacity. Burn-in 64 r18/19-proven.
__global__ __launch_bounds__(512, 6) void lstm_kernel(
    const float* __restrict__ xgF, const float* __restrict__ xgB,
    const float* __restrict__ WhhF, const float* __restrict__ WhhB,
    const float* __restrict__ h0, const float* __restrict__ c0,
    float* __restrict__ feats, int dirSel) {
  __shared__ __align__(16) unsigned int h16_s[2][32];  // packed f16 pairs of h[64]
  const int ck = blockIdx.x;           // 0..2
  const int b = blockIdx.y;            // 0..127
  const int d = (dirSel >= 0) ? dirSel : (int)blockIdx.z;
  const int tid = threadIdx.x;
  const int lane = tid & 63;
  const int w = tid >> 6;          // wave 0..7
  const int kh = lane >> 5;        // K half
  const int gt = (lane >> 3) & 3;  // gate type 0:i 1:f 2:g 3:o
  const int u = lane & 7;
  const int unit = 8 * w + u;
  const int row = gt * 64 + unit;  // W_hh row
  const float* xg = d ? xgB : xgF;
  const float* Whh = d ? WhhB : WhhF;
  // --- load 32 f32 weights, pack to 16 half2, pin in AGPRs ---
  float a00,a01,a02,a03,a04,a05,a06,a07,a08,a09,a10,a11,a12,a13,a14,a15;
  {
    const float4* wp = (const float4*)(Whh + (size_t)row * 64 + 32 * kh);
#define PK(A0, A1, Q) do {                                                     \
      const float4 wq = (Q);                                                   \
      U32H2 p0_, p1_;                                                          \
      p0_.h = __builtin_amdgcn_cvt_pkrtz(wq.x, wq.y);                          \
      p1_.h = __builtin_amdgcn_cvt_pkrtz(wq.z, wq.w);                          \
      asm volatile("v_accvgpr_write_b32 %0, %1" : "=a"(A0) : "v"(p0_.f));      \
      asm volatile("v_accvgpr_write_b32 %0, %1" : "=a"(A1) : "v"(p1_.f));      \
    } while (0)
    PK(a00, a01, wp[0]); PK(a02, a03, wp[1]);
    PK(a04, a05, wp[2]); PK(a06, a07, wp[3]);
    PK(a08, a09, wp[4]); PK(a10, a11, wp[5]);
    PK(a12, a13, wp[6]); PK(a14, a15, wp[7]);
#undef PK
  }
  const bool isT = (gt == 2);
  const float fA = isT ? 1.0f : 0.0f;
  const float fB = isT ? -2.0f : 1.0f;
  const float fC = isT ? 2.8853900817779268f : -1.4426950408889634f;
  float c = 0.f;
  if (lane < 8) {  // gt==0 && kh==0: unit owner
    float hv = 0.f;
    if (ck == 0) {
      c = c0[(size_t)d * (Bn * 64) + (size_t)b * 64 + unit];
      hv = h0[(size_t)d * (Bn * 64) + (size_t)b * 64 + unit];
    }
    const float hn = __shfl_xor(hv, 1);
    if ((u & 1) == 0) {
      U32H2 p; p.h = __builtin_amdgcn_cvt_pkrtz(hv, hn);
      h16_s[0][4 * w + (u >> 1)] = p.u;
    }
  }
  const float* xb = xg + (size_t)b * Tn * G4 + row;
  float* fbase = feats + (size_t)b * Tn * Hn + d * 64 + unit;
  const int t0 = d ? (Tn - 1) : 0;
  const int ts = d ? -1 : 1;
  // chunk geometry: (sLo, sW, sHi); all deltas multiples of 4, burns = 64
  const int sW  = (ck == 0) ? 0   : (ck == 1 ? 216 : 364);
  const int sLo = (ck == 0) ? 0   : (ck == 1 ? 152 : 300);
  const int sHi = (ck == 0) ? 216 : (ck == 1 ? 364 : 512);
  float p0 = 0.f, p1 = 0.f, p2 = 0.f, p3 = 0.f;
  if (kh == 0) {
    p0 = xb[(size_t)(t0 + (sLo + 0) * ts) * G4];
    p1 = xb[(size_t)(t0 + (sLo + 1) * ts) * G4];
    p2 = xb[(size_t)(t0 + (sLo + 2) * ts) * G4];
    p3 = xb[(size_t)(t0 + (sLo + 3) * ts) * G4];
  }

#define ARD8(U0,U1,U2,U3,U4,U5,U6,U7, A0,A1,A2,A3,A4,A5,A6,A7)                \
  asm volatile("v_accvgpr_read_b32 %0, %8\n\t"                                \
               "v_accvgpr_read_b32 %1, %9\n\t"                                \
               "v_accvgpr_read_b32 %2, %10\n\t"                               \
               "v_accvgpr_read_b32 %3, %11\n\t"                               \
               "v_accvgpr_read_b32 %4, %12\n\t"                               \
               "v_accvgpr_read_b32 %5, %13\n\t"                               \
               "v_accvgpr_read_b32 %6, %14\n\t"                               \
               "v_accvgpr_read_b32 %7, %15"                                   \
               : "=&v"(U0),"=&v"(U1),"=&v"(U2),"=&v"(U3),                     \
                 "=&v"(U4),"=&v"(U5),"=&v"(U6),"=&v"(U7)                      \
               : "a"(A0),"a"(A1),"a"(A2),"a"(A3),                             \
                 "a"(A4),"a"(A5),"a"(A6),"a"(A7))
#define H2F(F) (__builtin_bit_cast(h2_t, F))
#define H2U(UU) (__builtin_bit_cast(h2_t, UU))

#define LSTM_STEP(P, TT, RB, DW) do {                                          \
    wg_barrier();                                                              \
    const uint4* hp = (const uint4*)(&h16_s[RB][16 * kh]);                     \
    const uint4 q0 = hp[0], q1 = hp[1], q2 = hp[2], q3 = hp[3];                \
    float u00,u01,u02,u03,u04,u05,u06,u07,u08,u09,u10,u11,u12,u13,u14,u15;     \
    ARD8(u00,u01,u02,u03,u04,u05,u06,u07, a00,a01,a02,a03,a04,a05,a06,a07);    \
    ARD8(u08,u09,u10,u11,u12,u13,u14,u15, a08,a09,a10,a11,a12,a13,a14,a15);    \
    float s0 = 0.f, s1 = 0.f, s2 = 0.f, s3 = 0.f;                              \
    s0 = fdot2(H2U(q0.x), H2F(u00), s0);                                       \
    s1 = fdot2(H2U(q0.y), H2F(u01), s1);                                       \
    s2 = fdot2(H2U(q0.z), H2F(u02), s2);                                       \
    s3 = fdot2(H2U(q0.w), H2F(u03), s3);                                       \
    s0 = fdot2(H2U(q1.x), H2F(u04), s0);                                       \
    s1 = fdot2(H2U(q1.y), H2F(u05), s1);                                       \
    s2 = fdot2(H2U(q1.z), H2F(u06), s2);                                       \
    s3 = fdot2(H2U(q1.w), H2F(u07), s3);                                       \
    s0 = fdot2(H2U(q2.x), H2F(u08), s0);                                       \
    s1 = fdot2(H2U(q2.y), H2F(u09), s1);                                       \
    s2 = fdot2(H2U(q2.z), H2F(u10), s2);                                       \
    s3 = fdot2(H2U(q2.w), H2F(u11), s3);                                       \
    s0 = fdot2(H2U(q3.x), H2F(u12), s0);                                       \
    s1 = fdot2(H2U(q3.y), H2F(u13), s1);                                       \
    s2 = fdot2(H2U(q3.z), H2F(u14), s2);                                       \
    s3 = fdot2(H2U(q3.w), H2F(u15), s3);                                       \
    const float smine = (s0 + s1) + (s2 + s3);                                 \
    const float stot = smine + __shfl_xor(smine, 32);                          \
    const float accv = (P) + stot;                                             \
    const float act = fmaf(fB, rcp_hw(1.0f + exp2_hw(fC * accv)), fA);         \
    const float gF = __shfl_xor(act, 8);                                       \
    const float gG = __shfl_xor(act, 16);                                      \
    const float gO = __shfl_xor(act, 24);                                      \
    if (lane < 8) {                                                            \
      c = fmaf(gF, c, act * gG);                                               \
      const float hh = gO * fast_tanh(c);                                      \
      const float hn = __shfl_xor(hh, 1);                                      \
      if ((u & 1) == 0) {                                                      \
        U32H2 pz; pz.h = __builtin_amdgcn_cvt_pkrtz(hh, hn);                   \
        h16_s[(RB) ^ 1][4 * w + (u >> 1)] = pz.u;                              \
      }                                                                        \
      if (DW) fbase[(size_t)(TT) * Hn] = hh;                                   \
    }                                                                          \
  } while (0)

  for (int s = sLo; s < sHi; s += 4) {
    const int tA = t0 + s * ts;
    const bool dw = (s >= sW);
    LSTM_STEP(p0, tA, 0, dw);
    if (kh == 0 && s + 4 < sHi) p0 = xb[(size_t)(t0 + (s + 4) * ts) * G4];
    LSTM_STEP(p1, tA + ts, 1, dw);
    if (kh == 0 && s + 5 < sHi) p1 = xb[(size_t)(t0 + (s + 5) * ts) * G4];
    LSTM_STEP(p2, tA + 2 * ts, 0, dw);
    if (kh == 0 && s + 6 < sHi) p2 = xb[(size_t)(t0 + (s + 6) * ts) * G4];
    LSTM_STEP(p3, tA + 3 * ts, 1, dw);
    if (kh == 0 && s + 7 < sHi) p3 = xb[(size_t)(t0 + (s + 7) * ts) * G4];
  }
#undef LSTM_STEP
#undef H2U
#undef H2F
#undef ARD8
}

// ---------------- K3: emissions, 4-lane cooperative (r16) ----------------
__global__ __launch_bounds__(256) void emis_kernel(
    const float* __restrict__ feats, const float* __restrict__ Wout,
    const float* __restrict__ bout, float* __restrict__ em) {
  __shared__ __align__(16) float Wo[Kn * Hn];
  __shared__ float bo[Kn];
  const int tid = threadIdx.x;
  for (int i = tid; i < Kn * Hn; i += 256) Wo[i] = Wout[i];
  if (tid < Kn) bo[tid] = bout[tid];
  __syncthreads();
  const int q = tid & 3;
  const int n = blockIdx.x * 64 + (tid >> 2);
  float acc[Kn];
#pragma unroll
  for (int k = 0; k < Kn; ++k) acc[k] = 0.f;
  const float4* fp = (const float4*)(feats + (size_t)n * Hn);
#pragma unroll
  for (int c = 0; c < 8; ++c) {
    const float4 v = fp[q + 4 * c];
#pragma unroll
    for (int k = 0; k < Kn; ++k) {
      const float4 w = *(const float4*)&Wo[k * Hn + (q + 4 * c) * 4];
      acc[k] = fmaf(v.x, w.x, acc[k]);
      acc[k] = fmaf(v.y, w.y, acc[k]);
      acc[k] = fmaf(v.z, w.z, acc[k]);
      acc[k] = fmaf(v.w, w.w, acc[k]);
    }
  }
#pragma unroll
  for (int k = 0; k < Kn; ++k) {
    acc[k] += __shfl_xor(acc[k], 1);
    acc[k] += __shfl_xor(acc[k], 2);
  }
  float* ep = em + (size_t)n * Kn + 3 * q;
#pragma unroll
  for (int j = 0; j < 3; ++j) ep[j] = acc[3 * q + j] + bo[3 * q + j];
}

// ---------------- K4: Viterbi (pipelined em prefetch, r16) ----------------
#define AMAX(v, a, v2, a2) { if ((v2) > (v)) { (v) = (v2); (a) = (a2); } }

__global__ __launch_bounds__(64) void viterbi_kernel(
    const float* __restrict__ em, const float* __restrict__ trans,
    float* __restrict__ out) {
  __shared__ __align__(16) float em_s[Tn * Kn];
  __shared__ float trans_s[Kn * Kn];
  __shared__ unsigned char bp[(Tn - 1) * Kn];
  __shared__ short path_s[Tn];
  const int tid = threadIdx.x;
  const int b = blockIdx.x;
  {
    const float4* ebv = (const float4*)(em + (size_t)b * Tn * Kn);
    float4* emv = (float4*)em_s;
    for (int i = tid; i < (Tn * Kn) / 4; i += 64) emv[i] = ebv[i];
  }
  for (int i = tid; i < Kn * Kn; i += 64) trans_s[i] = trans[i];
  __syncthreads();
  const int lane = (tid < Kn) ? tid : 0;
  float treg[Kn];
#pragma unroll
  for (int f = 0; f < Kn; ++f) treg[f] = trans_s[f * Kn + lane];
  float prev = em_s[lane];
  float e_nx = em_s[Kn + lane];
  for (int t = 1; t < Tn; ++t) {
    float cv[Kn];
#pragma unroll
    for (int f = 0; f < Kn; ++f) cv[f] = __shfl(prev, f) + treg[f];
    const float e_use = e_nx;
    if (t + 1 < Tn) e_nx = em_s[(t + 1) * Kn + lane];
    float m0 = cv[0], m1 = cv[2], m2 = cv[4], m3 = cv[6], m4 = cv[8], m5 = cv[10];
    int a0 = 0, a1 = 2, a2 = 4, a3 = 6, a4 = 8, a5 = 10;
    AMAX(m0, a0, cv[1], 1);  AMAX(m1, a1, cv[3], 3);
    AMAX(m2, a2, cv[5], 5);  AMAX(m3, a3, cv[7], 7);
    AMAX(m4, a4, cv[9], 9);  AMAX(m5, a5, cv[11], 11);
    AMAX(m0, a0, m1, a1); AMAX(m2, a2, m3, a3); AMAX(m4, a4, m5, a5);
    AMAX(m0, a0, m2, a2); AMAX(m0, a0, m4, a4);
    prev = e_use + m0;
    if (tid < Kn) bp[(t - 1) * Kn + tid] = (unsigned char)a0;
  }
  float fv[Kn];
#pragma unroll
  for (int f = 0; f < Kn; ++f) fv[f] = __shfl(prev, f);
  float m0 = fv[0], m1 = fv[2], m2 = fv[4], m3 = fv[6], m4 = fv[8], m5 = fv[10];
  int a0 = 0, a1 = 2, a2 = 4, a3 = 6, a4 = 8, a5 = 10;
  AMAX(m0, a0, fv[1], 1);  AMAX(m1, a1, fv[3], 3);
  AMAX(m2, a2, fv[5], 5);  AMAX(m3, a3, fv[7], 7);
  AMAX(m4, a4, fv[9], 9);  AMAX(m5, a5, fv[11], 11);
  AMAX(m0, a0, m1, a1); AMAX(m2, a2, m3, a3); AMAX(m4, a4, m5, a5);
  AMAX(m0, a0, m2, a2); AMAX(m0, a0, m4, a4);
  __syncthreads();
  if (tid == 0) {
    out[b] = m0;
    int cur = a0;
    for (int i = Tn - 2; i >= 0; --i) {
      path_s[i + 1] = (short)cur;
      cur = bp[i * Kn + cur];
    }
    path_s[0] = (short)cur;
  }
  __syncthreads();
  for (int i = tid; i < Tn; i += 64)
    out[Bn + (size_t)b * Tn + i] = (float)path_s[i];
}

extern "C" void kernel_launch(void* const* d_in, const int* in_sizes, int n_in,
                              void* d_out, int out_size, void* d_ws, size_t ws_size,
                              hipStream_t stream) {
  const int*   sent  = (const int*)d_in[0];
  const float* embed = (const float*)d_in[1];
  const float* Wih_f = (const float*)d_in[2];
  const float* Whh_f = (const float*)d_in[3];
  const float* bih_f = (const float*)d_in[4];
  const float* bhh_f = (const float*)d_in[5];
  const float* Wih_b = (const float*)d_in[6];
  const float* Whh_b = (const float*)d_in[7];
  const float* bih_b = (const float*)d_in[8];
  const float* bhh_b = (const float*)d_in[9];
  const float* Wout  = (const float*)d_in[10];
  const float* bout  = (const float*)d_in[11];
  const float* trans = (const float*)d_in[12];
  const float* h0    = (const float*)d_in[13];
  const float* c0    = (const float*)d_in[14];
  float* out = (float*)d_out;

  char* ws = (char*)d_ws;
  const size_t xgBytes   = (size_t)Bn * Tn * G4 * sizeof(float);  // 64 MiB
  const size_t featBytes = (size_t)Bn * Tn * Hn * sizeof(float);  // 32 MiB
  const size_t emBytes   = (size_t)Bn * Tn * Kn * sizeof(float);  //  3 MiB
  const int tileBlocks = (Bn * Tn) / 256;  // 256 (4 token-tiles per block)

  if (ws_size >= 2 * xgBytes + featBytes + emBytes) {
    float* xgF   = (float*)ws;
    float* xgB   = (float*)(ws + xgBytes);
    float* feats = (float*)(ws + 2 * xgBytes);
    float* emis  = (float*)(ws + 2 * xgBytes + featBytes);
    proj_kernel<<<dim3(tileBlocks, 2, 2), 256, 0, stream>>>(
        sent, embed, Wih_f, Wih_b, bih_f, bhh_f, bih_b, bhh_b, xgF, xgB, -1);
    lstm_kernel<<<dim3(3, 128, 2), 512, 0, stream>>>(
        xgF, xgB, Whh_f, Whh_b, h0, c0, feats, -1);
    emis_kernel<<<1024, 256, 0, stream>>>(feats, Wout, bout, emis);
    viterbi_kernel<<<128, 64, 0, stream>>>(emis, trans, out);
  } else {
    float* xgS   = (float*)ws;
    float* feats = (float*)(ws + xgBytes);
    float* emis  = (float*)(ws + xgBytes + featBytes);
    proj_kernel<<<dim3(tileBlocks, 2, 1), 256, 0, stream>>>(
        sent, embed, Wih_f, Wih_b, bih_f, bhh_f, bih_b, bhh_b, xgS, xgS, 0);
    lstm_kernel<<<dim3(3, 128, 1), 512, 0, stream>>>(
        xgS, xgS, Whh_f, Whh_f, h0, c0, feats, 0);
    proj_kernel<<<dim3(tileBlocks, 2, 1), 256, 0, stream>>>(
        sent, embed, Wih_f, Wih_b, bih_f, bhh_f, bih_b, bhh_b, xgS, xgS, 1);
    lstm_kernel<<<dim3(3, 128, 1), 512, 0, stream>>>(
        xgS, xgS, Whh_b, Whh_b, h0, c0, feats, 1);
    emis_kernel<<<1024, 256, 0, stream>>>(feats, Wout, bout, emis);
    viterbi_kernel<<<128, 64, 0, stream>>>(emis, trans, out);
  }
}

// Round 23
// 356.848 us; speedup vs baseline: 1.0279x; 1.0279x over previous
//
#include <hip/hip_runtime.h>
#include <hip/hip_bf16.h>

#define Bn 128
#define Tn 512
#define En 100
#define G4 256   // 4*HD
#define Hn 128
#define Kn 12

typedef short bf16x8 __attribute__((ext_vector_type(8)));
typedef float f32x4 __attribute__((ext_vector_type(4)));
// exact type the AMDGCN packed-half builtins use
using h2_t = decltype(__builtin_amdgcn_cvt_pkrtz(0.0f, 0.0f));
union U32H2 { unsigned int u; float f; h2_t h; };

// Raw barrier: lgkmcnt(0) + s_barrier, no vmcnt drain (prefetch survives).
__device__ __forceinline__ void wg_barrier() {
  asm volatile("s_waitcnt lgkmcnt(0)" ::: "memory");
  __builtin_amdgcn_s_barrier();
  asm volatile("" ::: "memory");
}

__device__ __forceinline__ float exp2_hw(float x) {
  float r; asm("v_exp_f32 %0, %1" : "=v"(r) : "v"(x)); return r;
}
__device__ __forceinline__ float rcp_hw(float x) {
  float r; asm("v_rcp_f32 %0, %1" : "=v"(r) : "v"(x)); return r;
}
__device__ __forceinline__ float fast_tanh(float x) {
  return 1.0f - 2.0f * rcp_hw(1.0f + exp2_hw(x * 2.8853900817779268f));
}
__device__ __forceinline__ float fdot2(h2_t a, h2_t b, float c) {
#if __has_builtin(__builtin_amdgcn_fdot2)
  return __builtin_amdgcn_fdot2(a, b, c, false);
#else
  float r;
  asm("v_dot2_f32_f16 %0, %1, %2, %3" : "=v"(r) : "v"(a), "v"(b), "v"(c));
  return r;
#endif
}
// pack 2 floats -> 2 bf16 (RNE) in one u32
__device__ __forceinline__ unsigned int pk2bf(float a, float b) {
  unsigned int ua = __float_as_uint(a); ua += 0x7FFFu + ((ua >> 16) & 1u);
  unsigned int ub = __float_as_uint(b); ub += 0x7FFFu + ((ub >> 16) & 1u);
  return (ua >> 16) | (ub & 0xFFFF0000u);
}

// ---------------- K1: proj via MFMA bf16, 4 token-tiles/block (r21) -------
// W_ih tile (128x128 bf16) and bias staged ONCE per block, reused across 4
// token-tiles (4x less W re-read L2 traffic vs r10). emb staged per tile.
__global__ __launch_bounds__(256) void proj_kernel(
    const int* __restrict__ sent, const float* __restrict__ embed,
    const float* __restrict__ WihF, const float* __restrict__ WihB,
    const float* __restrict__ bihF, const float* __restrict__ bhhF,
    const float* __restrict__ bihB, const float* __restrict__ bhhB,
    float* __restrict__ xgF, float* __restrict__ xgB, int dirSel) {
  __shared__ __align__(16) unsigned short embS[64][128];
  __shared__ __align__(16) unsigned short wS[128][128];
  __shared__ float bias_s[128];
  const int tid = threadIdx.x;
  const int nhalf = blockIdx.y;
  const int dir = (dirSel >= 0) ? dirSel : (int)blockIdx.z;
  const float* Wih = dir ? WihB : WihF;
  const float* bih = dir ? bihB : bihF;
  const float* bhh = dir ? bhhB : bhhF;
  float* xg = dir ? xgB : xgF;
  const int g0 = nhalf * 128;
  // --- stage W once ---
  {
    const int r = tid >> 1, q = tid & 1;
    const float* wr = Wih + (size_t)(g0 + r) * En;
    for (int c = q; c < 16; c += 2) {
      uint4 wv;
      if (c < 12) {
        const float4 f0 = *(const float4*)(wr + 8 * c);
        const float4 f1 = *(const float4*)(wr + 8 * c + 4);
        wv = make_uint4(pk2bf(f0.x, f0.y), pk2bf(f0.z, f0.w),
                        pk2bf(f1.x, f1.y), pk2bf(f1.z, f1.w));
      } else if (c == 12) {
        float f[8];
#pragma unroll
        for (int j = 0; j < 8; ++j) { const int e = 96 + j; f[j] = (e < En) ? wr[e] : 0.f; }
        wv = make_uint4(pk2bf(f[0], f[1]), pk2bf(f[2], f[3]),
                        pk2bf(f[4], f[5]), pk2bf(f[6], f[7]));
      } else {
        wv = make_uint4(0, 0, 0, 0);
      }
      *(uint4*)&wS[r][8 * (c ^ (r & 7))] = wv;
    }
    if (tid < 128) bias_s[tid] = bih[g0 + tid] + bhh[g0 + tid];
  }
  const int m = tid >> 6;
  const int lane = tid & 63;
  const int lr = lane & 15;
  const int lq = lane >> 4;
  const int t = 16 * m + lr;
  for (int tt = 0; tt < 4; ++tt) {
    const int n0 = (blockIdx.x * 4 + tt) * 64;
    // --- stage emb for this tile ---
    {
      const int tr = tid >> 2, q = tid & 3;
      const int row = sent[n0 + tr];
      const float* er = embed + (size_t)row * En;
      for (int c = q; c < 16; c += 4) {
        uint4 wv;
        if (c < 12) {
          const float4 f0 = *(const float4*)(er + 8 * c);
          const float4 f1 = *(const float4*)(er + 8 * c + 4);
          wv = make_uint4(pk2bf(f0.x, f0.y), pk2bf(f0.z, f0.w),
                          pk2bf(f1.x, f1.y), pk2bf(f1.z, f1.w));
        } else if (c == 12) {
          float f[8];
#pragma unroll
          for (int j = 0; j < 8; ++j) { const int e = 96 + j; f[j] = (e < En) ? er[e] : 0.f; }
          wv = make_uint4(pk2bf(f[0], f[1]), pk2bf(f[2], f[3]),
                          pk2bf(f[4], f[5]), pk2bf(f[6], f[7]));
        } else {
          wv = make_uint4(0, 0, 0, 0);
        }
        *(uint4*)&embS[tr][8 * (c ^ (tr & 7))] = wv;
      }
    }
    __syncthreads();
    f32x4 acc[8] = {};
#pragma unroll
    for (int ks = 0; ks < 4; ++ks) {
      const int cs = 4 * ks + lq;
      const bf16x8 af = *(const bf16x8*)&embS[t][8 * (cs ^ (lr & 7))];
#pragma unroll
      for (int nt = 0; nt < 8; ++nt) {
        const int g = 16 * nt + lr;
        const bf16x8 bf = *(const bf16x8*)&wS[g][8 * (cs ^ (lr & 7))];
        acc[nt] = __builtin_amdgcn_mfma_f32_16x16x32_bf16(af, bf, acc[nt], 0, 0, 0);
      }
    }
    float* xbase = xg + (size_t)(n0 + 16 * m) * G4 + g0;
#pragma unroll
    for (int nt = 0; nt < 8; ++nt) {
      const int g = 16 * nt + lr;
      const float bv = bias_s[g];
#pragma unroll
      for (int j = 0; j < 4; ++j) {
        const int tok = 4 * lq + j;
        xbase[(size_t)tok * G4 + g] = acc[nt][j] + bv;
      }
    }
    __syncthreads();
  }
}

// ---------------- K2: LSTM (r19/r21 optimum: f16-dot2, 2 T-chunks) --------
// Best measured: 199 us. Chunk-count curve is convex with min at 2
// (2:199, 3:211, 4:274) — issue demand per SIMD governs. 16 AGPR-packed
// half2 + 16 v_dot2_f32_f16 per step; ck1 zero-starts at s=224, burns 64.
__global__ __launch_bounds__(512, 2) void lstm_kernel(
    const float* __restrict__ xgF, const float* __restrict__ xgB,
    const float* __restrict__ WhhF, const float* __restrict__ WhhB,
    const float* __restrict__ h0, const float* __restrict__ c0,
    float* __restrict__ feats, int dirSel) {
  __shared__ __align__(16) unsigned int h16_s[2][32];  // packed f16 pairs of h[64]
  int d, b, ck;
  if (dirSel < 0) { d = blockIdx.x >> 8; b = (blockIdx.x >> 1) & 127; ck = blockIdx.x & 1; }
  else            { d = dirSel;          b = blockIdx.x >> 1;         ck = blockIdx.x & 1; }
  const int tid = threadIdx.x;
  const int lane = tid & 63;
  const int w = tid >> 6;          // wave 0..7
  const int kh = lane >> 5;        // K half
  const int gt = (lane >> 3) & 3;  // gate type 0:i 1:f 2:g 3:o
  const int u = lane & 7;
  const int unit = 8 * w + u;
  const int row = gt * 64 + unit;  // W_hh row
  const float* xg = d ? xgB : xgF;
  const float* Whh = d ? WhhB : WhhF;
  // --- load 32 f32 weights, pack to 16 half2, pin in AGPRs ---
  float a00,a01,a02,a03,a04,a05,a06,a07,a08,a09,a10,a11,a12,a13,a14,a15;
  {
    const float4* wp = (const float4*)(Whh + (size_t)row * 64 + 32 * kh);
#define PK(A0, A1, Q) do {                                                     \
      const float4 wq = (Q);                                                   \
      U32H2 p0_, p1_;                                                          \
      p0_.h = __builtin_amdgcn_cvt_pkrtz(wq.x, wq.y);                          \
      p1_.h = __builtin_amdgcn_cvt_pkrtz(wq.z, wq.w);                          \
      asm volatile("v_accvgpr_write_b32 %0, %1" : "=a"(A0) : "v"(p0_.f));      \
      asm volatile("v_accvgpr_write_b32 %0, %1" : "=a"(A1) : "v"(p1_.f));      \
    } while (0)
    PK(a00, a01, wp[0]); PK(a02, a03, wp[1]);
    PK(a04, a05, wp[2]); PK(a06, a07, wp[3]);
    PK(a08, a09, wp[4]); PK(a10, a11, wp[5]);
    PK(a12, a13, wp[6]); PK(a14, a15, wp[7]);
#undef PK
  }
  const bool isT = (gt == 2);
  const float fA = isT ? 1.0f : 0.0f;
  const float fB = isT ? -2.0f : 1.0f;
  const float fC = isT ? 2.8853900817779268f : -1.4426950408889634f;
  float c = 0.f;
  if (lane < 8) {  // gt==0 && kh==0: unit owner
    float hv = 0.f;
    if (ck == 0) {
      c = c0[(size_t)d * (Bn * 64) + (size_t)b * 64 + unit];
      hv = h0[(size_t)d * (Bn * 64) + (size_t)b * 64 + unit];
    }
    const float hn = __shfl_xor(hv, 1);
    if ((u & 1) == 0) {
      U32H2 p; p.h = __builtin_amdgcn_cvt_pkrtz(hv, hn);
      h16_s[0][4 * w + (u >> 1)] = p.u;
    }
  }
  const float* xb = xg + (size_t)b * Tn * G4 + row;
  float* fbase = feats + (size_t)b * Tn * Hn + d * 64 + unit;
  const int t0 = d ? (Tn - 1) : 0;
  const int ts = d ? -1 : 1;
  const int sLo = ck ? 224 : 0;    // first computed s (ck1: burn-in start)
  const int sHi = ck ? Tn : 288;   // end of range
  const int sW  = ck ? 288 : 0;    // first stored s
  float p0 = 0.f, p1 = 0.f, p2 = 0.f, p3 = 0.f;
  if (kh == 0) {
    p0 = xb[(size_t)(t0 + (sLo + 0) * ts) * G4];
    p1 = xb[(size_t)(t0 + (sLo + 1) * ts) * G4];
    p2 = xb[(size_t)(t0 + (sLo + 2) * ts) * G4];
    p3 = xb[(size_t)(t0 + (sLo + 3) * ts) * G4];
  }

#define ARD8(U0,U1,U2,U3,U4,U5,U6,U7, A0,A1,A2,A3,A4,A5,A6,A7)                \
  asm volatile("v_accvgpr_read_b32 %0, %8\n\t"                                \
               "v_accvgpr_read_b32 %1, %9\n\t"                                \
               "v_accvgpr_read_b32 %2, %10\n\t"                               \
               "v_accvgpr_read_b32 %3, %11\n\t"                               \
               "v_accvgpr_read_b32 %4, %12\n\t"                               \
               "v_accvgpr_read_b32 %5, %13\n\t"                               \
               "v_accvgpr_read_b32 %6, %14\n\t"                               \
               "v_accvgpr_read_b32 %7, %15"                                   \
               : "=&v"(U0),"=&v"(U1),"=&v"(U2),"=&v"(U3),                     \
                 "=&v"(U4),"=&v"(U5),"=&v"(U6),"=&v"(U7)                      \
               : "a"(A0),"a"(A1),"a"(A2),"a"(A3),                             \
                 "a"(A4),"a"(A5),"a"(A6),"a"(A7))
#define H2F(F) (__builtin_bit_cast(h2_t, F))
#define H2U(UU) (__builtin_bit_cast(h2_t, UU))

#define LSTM_STEP(P, TT, RB, DW) do {                                          \
    wg_barrier();                                                              \
    const uint4* hp = (const uint4*)(&h16_s[RB][16 * kh]);                     \
    const uint4 q0 = hp[0], q1 = hp[1], q2 = hp[2], q3 = hp[3];                \
    float u00,u01,u02,u03,u04,u05,u06,u07,u08,u09,u10,u11,u12,u13,u14,u15;     \
    ARD8(u00,u01,u02,u03,u04,u05,u06,u07, a00,a01,a02,a03,a04,a05,a06,a07);    \
    ARD8(u08,u09,u10,u11,u12,u13,u14,u15, a08,a09,a10,a11,a12,a13,a14,a15);    \
    float s0 = 0.f, s1 = 0.f, s2 = 0.f, s3 = 0.f;                              \
    s0 = fdot2(H2U(q0.x), H2F(u00), s0);                                       \
    s1 = fdot2(H2U(q0.y), H2F(u01), s1);                                       \
    s2 = fdot2(H2U(q0.z), H2F(u02), s2);                                       \
    s3 = fdot2(H2U(q0.w), H2F(u03), s3);                                       \
    s0 = fdot2(H2U(q1.x), H2F(u04), s0);                                       \
    s1 = fdot2(H2U(q1.y), H2F(u05), s1);                                       \
    s2 = fdot2(H2U(q1.z), H2F(u06), s2);                                       \
    s3 = fdot2(H2U(q1.w), H2F(u07), s3);                                       \
    s0 = fdot2(H2U(q2.x), H2F(u08), s0);                                       \
    s1 = fdot2(H2U(q2.y), H2F(u09), s1);                                       \
    s2 = fdot2(H2U(q2.z), H2F(u10), s2);                                       \
    s3 = fdot2(H2U(q2.w), H2F(u11), s3);                                       \
    s0 = fdot2(H2U(q3.x), H2F(u12), s0);                                       \
    s1 = fdot2(H2U(q3.y), H2F(u13), s1);                                       \
    s2 = fdot2(H2U(q3.z), H2F(u14), s2);                                       \
    s3 = fdot2(H2U(q3.w), H2F(u15), s3);                                       \
    const float smine = (s0 + s1) + (s2 + s3);                                 \
    const float stot = smine + __shfl_xor(smine, 32);                          \
    const float accv = (P) + stot;                                             \
    const float act = fmaf(fB, rcp_hw(1.0f + exp2_hw(fC * accv)), fA);         \
    const float gF = __shfl_xor(act, 8);                                       \
    const float gG = __shfl_xor(act, 16);                                      \
    const float gO = __shfl_xor(act, 24);                                      \
    if (lane < 8) {                                                            \
      c = fmaf(gF, c, act * gG);                                               \
      const float hh = gO * fast_tanh(c);                                      \
      const float hn = __shfl_xor(hh, 1);                                      \
      if ((u & 1) == 0) {                                                      \
        U32H2 pz; pz.h = __builtin_amdgcn_cvt_pkrtz(hh, hn);                   \
        h16_s[(RB) ^ 1][4 * w + (u >> 1)] = pz.u;                              \
      }                                                                        \
      if (DW) fbase[(size_t)(TT) * Hn] = hh;                                   \
    }                                                                          \
  } while (0)

  for (int s = sLo; s < sHi; s += 4) {
    const int tA = t0 + s * ts;
    const bool dw = (s >= sW);
    LSTM_STEP(p0, tA, 0, dw);
    if (kh == 0 && s + 4 < sHi) p0 = xb[(size_t)(t0 + (s + 4) * ts) * G4];
    LSTM_STEP(p1, tA + ts, 1, dw);
    if (kh == 0 && s + 5 < sHi) p1 = xb[(size_t)(t0 + (s + 5) * ts) * G4];
    LSTM_STEP(p2, tA + 2 * ts, 0, dw);
    if (kh == 0 && s + 6 < sHi) p2 = xb[(size_t)(t0 + (s + 6) * ts) * G4];
    LSTM_STEP(p3, tA + 3 * ts, 1, dw);
    if (kh == 0 && s + 7 < sHi) p3 = xb[(size_t)(t0 + (s + 7) * ts) * G4];
  }
#undef LSTM_STEP
#undef H2U
#undef H2F
#undef ARD8
}

// ---------------- K3: emissions, 4-lane cooperative (r16) ----------------
__global__ __launch_bounds__(256) void emis_kernel(
    const float* __restrict__ feats, const float* __restrict__ Wout,
    const float* __restrict__ bout, float* __restrict__ em) {
  __shared__ __align__(16) float Wo[Kn * Hn];
  __shared__ float bo[Kn];
  const int tid = threadIdx.x;
  for (int i = tid; i < Kn * Hn; i += 256) Wo[i] = Wout[i];
  if (tid < Kn) bo[tid] = bout[tid];
  __syncthreads();
  const int q = tid & 3;
  const int n = blockIdx.x * 64 + (tid >> 2);
  float acc[Kn];
#pragma unroll
  for (int k = 0; k < Kn; ++k) acc[k] = 0.f;
  const float4* fp = (const float4*)(feats + (size_t)n * Hn);
#pragma unroll
  for (int c = 0; c < 8; ++c) {
    const float4 v = fp[q + 4 * c];
#pragma unroll
    for (int k = 0; k < Kn; ++k) {
      const float4 w = *(const float4*)&Wo[k * Hn + (q + 4 * c) * 4];
      acc[k] = fmaf(v.x, w.x, acc[k]);
      acc[k] = fmaf(v.y, w.y, acc[k]);
      acc[k] = fmaf(v.z, w.z, acc[k]);
      acc[k] = fmaf(v.w, w.w, acc[k]);
    }
  }
#pragma unroll
  for (int k = 0; k < Kn; ++k) {
    acc[k] += __shfl_xor(acc[k], 1);
    acc[k] += __shfl_xor(acc[k], 2);
  }
  float* ep = em + (size_t)n * Kn + 3 * q;
#pragma unroll
  for (int j = 0; j < 3; ++j) ep[j] = acc[3 * q + j] + bo[3 * q + j];
}

// ---------------- K4: Viterbi (pipelined em prefetch, r16) ----------------
#define AMAX(v, a, v2, a2) { if ((v2) > (v)) { (v) = (v2); (a) = (a2); } }

__global__ __launch_bounds__(64) void viterbi_kernel(
    const float* __restrict__ em, const float* __restrict__ trans,
    float* __restrict__ out) {
  __shared__ __align__(16) float em_s[Tn * Kn];
  __shared__ float trans_s[Kn * Kn];
  __shared__ unsigned char bp[(Tn - 1) * Kn];
  __shared__ short path_s[Tn];
  const int tid = threadIdx.x;
  const int b = blockIdx.x;
  {
    const float4* ebv = (const float4*)(em + (size_t)b * Tn * Kn);
    float4* emv = (float4*)em_s;
    for (int i = tid; i < (Tn * Kn) / 4; i += 64) emv[i] = ebv[i];
  }
  for (int i = tid; i < Kn * Kn; i += 64) trans_s[i] = trans[i];
  __syncthreads();
  const int lane = (tid < Kn) ? tid : 0;
  float treg[Kn];
#pragma unroll
  for (int f = 0; f < Kn; ++f) treg[f] = trans_s[f * Kn + lane];
  float prev = em_s[lane];
  float e_nx = em_s[Kn + lane];
  for (int t = 1; t < Tn; ++t) {
    float cv[Kn];
#pragma unroll
    for (int f = 0; f < Kn; ++f) cv[f] = __shfl(prev, f) + treg[f];
    const float e_use = e_nx;
    if (t + 1 < Tn) e_nx = em_s[(t + 1) * Kn + lane];
    float m0 = cv[0], m1 = cv[2], m2 = cv[4], m3 = cv[6], m4 = cv[8], m5 = cv[10];
    int a0 = 0, a1 = 2, a2 = 4, a3 = 6, a4 = 8, a5 = 10;
    AMAX(m0, a0, cv[1], 1);  AMAX(m1, a1, cv[3], 3);
    AMAX(m2, a2, cv[5], 5);  AMAX(m3, a3, cv[7], 7);
    AMAX(m4, a4, cv[9], 9);  AMAX(m5, a5, cv[11], 11);
    AMAX(m0, a0, m1, a1); AMAX(m2, a2, m3, a3); AMAX(m4, a4, m5, a5);
    AMAX(m0, a0, m2, a2); AMAX(m0, a0, m4, a4);
    prev = e_use + m0;
    if (tid < Kn) bp[(t - 1) * Kn + tid] = (unsigned char)a0;
  }
  float fv[Kn];
#pragma unroll
  for (int f = 0; f < Kn; ++f) fv[f] = __shfl(prev, f);
  float m0 = fv[0], m1 = fv[2], m2 = fv[4], m3 = fv[6], m4 = fv[8], m5 = fv[10];
  int a0 = 0, a1 = 2, a2 = 4, a3 = 6, a4 = 8, a5 = 10;
  AMAX(m0, a0, fv[1], 1);  AMAX(m1, a1, fv[3], 3);
  AMAX(m2, a2, fv[5], 5);  AMAX(m3, a3, fv[7], 7);
  AMAX(m4, a4, fv[9], 9);  AMAX(m5, a5, fv[11], 11);
  AMAX(m0, a0, m1, a1); AMAX(m2, a2, m3, a3); AMAX(m4, a4, m5, a5);
  AMAX(m0, a0, m2, a2); AMAX(m0, a0, m4, a4);
  __syncthreads();
  if (tid == 0) {
    out[b] = m0;
    int cur = a0;
    for (int i = Tn - 2; i >= 0; --i) {
      path_s[i + 1] = (short)cur;
      cur = bp[i * Kn + cur];
    }
    path_s[0] = (short)cur;
  }
  __syncthreads();
  for (int i = tid; i < Tn; i += 64)
    out[Bn + (size_t)b * Tn + i] = (float)path_s[i];
}

extern "C" void kernel_launch(void* const* d_in, const int* in_sizes, int n_in,
                              void* d_out, int out_size, void* d_ws, size_t ws_size,
                              hipStream_t stream) {
  const int*   sent  = (const int*)d_in[0];
  const float* embed = (const float*)d_in[1];
  const float* Wih_f = (const float*)d_in[2];
  const float* Whh_f = (const float*)d_in[3];
  const float* bih_f = (const float*)d_in[4];
  const float* bhh_f = (const float*)d_in[5];
  const float* Wih_b = (const float*)d_in[6];
  const float* Whh_b = (const float*)d_in[7];
  const float* bih_b = (const float*)d_in[8];
  const float* bhh_b = (const float*)d_in[9];
  const float* Wout  = (const float*)d_in[10];
  const float* bout  = (const float*)d_in[11];
  const float* trans = (const float*)d_in[12];
  const float* h0    = (const float*)d_in[13];
  const float* c0    = (const float*)d_in[14];
  float* out = (float*)d_out;

  char* ws = (char*)d_ws;
  const size_t xgBytes   = (size_t)Bn * Tn * G4 * sizeof(float);  // 64 MiB
  const size_t featBytes = (size_t)Bn * Tn * Hn * sizeof(float);  // 32 MiB
  const size_t emBytes   = (size_t)Bn * Tn * Kn * sizeof(float);  //  3 MiB
  const int tileBlocks = (Bn * Tn) / 256;  // 256 (4 token-tiles per block)

  if (ws_size >= 2 * xgBytes + featBytes + emBytes) {
    float* xgF   = (float*)ws;
    float* xgB   = (float*)(ws + xgBytes);
    float* feats = (float*)(ws + 2 * xgBytes);
    float* emis  = (float*)(ws + 2 * xgBytes + featBytes);
    proj_kernel<<<dim3(tileBlocks, 2, 2), 256, 0, stream>>>(
        sent, embed, Wih_f, Wih_b, bih_f, bhh_f, bih_b, bhh_b, xgF, xgB, -1);
    lstm_kernel<<<512, 512, 0, stream>>>(xgF, xgB, Whh_f, Whh_b, h0, c0, feats, -1);
    emis_kernel<<<1024, 256, 0, stream>>>(feats, Wout, bout, emis);
    viterbi_kernel<<<128, 64, 0, stream>>>(emis, trans, out);
  } else {
    float* xgS   = (float*)ws;
    float* feats = (float*)(ws + xgBytes);
    float* emis  = (float*)(ws + xgBytes + featBytes);
    proj_kernel<<<dim3(tileBlocks, 2, 1), 256, 0, stream>>>(
        sent, embed, Wih_f, Wih_b, bih_f, bhh_f, bih_b, bhh_b, xgS, xgS, 0);
    lstm_kernel<<<256, 512, 0, stream>>>(xgS, xgS, Whh_f, Whh_f, h0, c0, feats, 0);
    proj_kernel<<<dim3(tileBlocks, 2, 1), 256, 0, stream>>>(
        sent, embed, Wih_f, Wih_b, bih_f, bhh_f, bih_b, bhh_b, xgS, xgS, 1);
    lstm_kernel<<<256, 512, 0, stream>>>(xgS, xgS, Whh_b, Whh_b, h0, c0, feats, 1);
    emis_kernel<<<1024, 256, 0, stream>>>(feats, Wout, bout, emis);
    viterbi_kernel<<<128, 64, 0, stream>>>(emis, trans, out);
  }
}